// Round 9
// baseline (376.882 us; speedup 1.0000x reference)
//
#include <hip/hip_runtime.h>
#include <hip/hip_bf16.h>

#define NPAT 50000
#define NCON 20000
#define NN   70000
#define EE   800000
#define H    128

#define NCON_AL  20032                 // concepts padded to 64-alignment
#define SEGN     (NCON_AL + NPAT)      // 70032 segment ids
#define NBUCK    1095                  // ceil(SEGN/64)
#define RELSPLIT_B 313                 // buckets [0,313) = concept dsts (rel0)
#define BUCKCAP  5120                  // pairs capacity per bucket (max fill ~2900)
#define SUBS     16                    // sub-regions per bucket (reservation slots)
#define SUBCAP   (BUCKCAP / SUBS)      // 320 (max fill ~236)
#define BPE      4096                  // edges per binpack block
#define NBB      ((2 * EE + BPE - 1) / BPE)   // 391
#define CAP      4096                  // LDS edge capacity per bucket (max ~2900)
#define STR      136                   // LDS row stride (shorts) for sX/sAgg; 272B = 16B-aligned

typedef __attribute__((ext_vector_type(8))) short bf16x8;
typedef __attribute__((ext_vector_type(4))) float f32x4;

__device__ inline unsigned short f2bf(float f) {
    unsigned u = __float_as_uint(f);
    unsigned r = (u + 0x7FFFu + ((u >> 16) & 1u)) >> 16;
    return (unsigned short)r;
}
__device__ inline float bf2f_lo(unsigned v) { return __uint_as_float(v << 16); }
__device__ inline float bf2f_hi(unsigned v) { return __uint_as_float(v & 0xFFFF0000u); }

// ============ init: per-(bucket,sub) cursors at static bases ============
__global__ void init_gcur_kernel(int* __restrict__ gcur) {
    int j = blockIdx.x * 256 + threadIdx.x;
    if (j < NBUCK * SUBS) gcur[j] = (j >> 4) * BUCKCAP + (j & (SUBS - 1)) * SUBCAP;
}

// ============ binpack: 512 thr, LDS counting sort by bucket, run-reserve, write ====
__global__ __launch_bounds__(512) void binpack_kernel(
        const int* __restrict__ dst_pc, const int* __restrict__ src_pc,
        const int* __restrict__ dst_cp, const int* __restrict__ src_cp,
        int* __restrict__ gcur, unsigned* __restrict__ pairs) {
    __shared__ unsigned sval[BPE];           // 16 KB
    __shared__ unsigned short sbkt[BPE];     // 8 KB
    __shared__ int cnt[NBUCK];               // 4.4 KB (then local cursor)
    __shared__ int delta[NBUCK];             // 4.4 KB
    __shared__ int partial[512];
    int t = threadIdx.x, blk = blockIdx.x;
    int base = blk * BPE;
    int n = min(BPE, 2 * EE - base);

    for (int i = t; i < NBUCK; i += 512) cnt[i] = 0;
    __syncthreads();

    unsigned pay[8];
    int bkt[8];
#pragma unroll
    for (int q = 0; q < 8; q++) {
        int li = q * 512 + t;
        bkt[q] = -1;
        if (li < n) {
            int i = base + li;
            int seg, src;
            if (i < EE) { seg = dst_pc[i];                src = src_pc[i]; }
            else        { seg = NCON_AL + dst_cp[i - EE]; src = src_cp[i - EE]; }
            int b = seg >> 6;
            pay[q] = (unsigned)src | ((unsigned)(seg & 63) << 16);
            bkt[q] = b;
            atomicAdd(&cnt[b], 1);
        }
    }
    __syncthreads();

    const int PER = (NBUCK + 511) / 512;   // 3
    int beg = t * PER;
    int s = 0;
#pragma unroll
    for (int k = 0; k < PER; k++) { int i = beg + k; if (i < NBUCK) s += cnt[i]; }
    partial[t] = s;
    __syncthreads();
    for (int o = 1; o < 512; o <<= 1) {
        int v = (t >= o) ? partial[t - o] : 0;
        __syncthreads();
        partial[t] += v;
        __syncthreads();
    }
    int run = partial[t] - s;
    int sub = blk & (SUBS - 1);
    int prefk[PER];
#pragma unroll
    for (int k = 0; k < PER; k++) {
        int i = beg + k;
        if (i < NBUCK) {
            prefk[k] = run;
            int c = cnt[i];
            if (c > 0) {
                int gb = atomicAdd(&gcur[i * SUBS + sub], c);
                delta[i] = gb - run;
            }
            run += c;
        }
    }
    __syncthreads();
#pragma unroll
    for (int k = 0; k < PER; k++) { int i = beg + k; if (i < NBUCK) cnt[i] = prefk[k]; }
    __syncthreads();

#pragma unroll
    for (int q = 0; q < 8; q++) {
        if (bkt[q] >= 0) {
            int b = bkt[q];
            int pos = atomicAdd(&cnt[b], 1);
            sval[pos] = pay[q];
            sbkt[pos] = (unsigned short)b;
        }
    }
    __syncthreads();
    for (int i = t; i < n; i += 512)
        pairs[delta[sbkt[i]] + i] = sval[i];
}

// ============ fused layer: sort + gather-aggregate (LDS) + MFMA GEMM ============
// block = bucket = 64 output rows. C[64][128] = x_rows@Wroot + agg@Wrel + bias, relu.
__global__ __launch_bounds__(512) void layer_fused_kernel(
        const unsigned short* __restrict__ xin,   // [NN][H] bf16
        const unsigned* __restrict__ pairs,
        const int* __restrict__ gcur,
        const float* __restrict__ Wroot,          // [128][128] fp32 k-major
        const float* __restrict__ WrelC,          // W_rel[l,0] (concept-dst)
        const float* __restrict__ WrelP,          // W_rel[l,1] (patient-dst)
        const float* __restrict__ bias,           // [128]
        float* __restrict__ Cout,                 // fp32 [NN][H] or null
        unsigned short* __restrict__ Cbf) {       // bf16 [NN][H] or null
    __shared__ unsigned short ssrc[CAP];          // 8 KB
    __shared__ unsigned short sX[64][STR];        // 17 KB  (this block's 64 xin rows)
    __shared__ unsigned short sAgg[64][STR];      // 17 KB  (aggregated rows, bf16)
    __shared__ unsigned short sBT[128][40];       // 10 KB  ([n][k] bf16 weight tile)
    __shared__ int cnt64[64];
    __shared__ int soff[65];
    __shared__ int scur[64];

    int t = threadIdx.x, b = blockIdx.x;
    bool isCon = (b < RELSPLIT_B);
    int wv = t >> 6, lane = t & 63;

    // ---- phase 0: stage this bucket's 64 xin rows (A1) into sX, coalesced
    int row0 = isCon ? (NPAT + b * 64) : ((b - RELSPLIT_B) * 64);
    int rowclamp = (isCon ? NN : NPAT) - 1;
    {
        // 64 rows x 16 uint4 = 1024 loads; 2 per thread
#pragma unroll
        for (int e = 0; e < 2; e++) {
            int idx = t * 2 + e;
            int r = idx >> 4, q = idx & 15;
            int gr = min(row0 + r, rowclamp);
            uint4 v = *(const uint4*)&xin[(size_t)gr * H + q * 8];
            *(uint4*)&sX[r][q * 8] = v;
        }
    }
    if (t < 64) cnt64[t] = 0;
    __syncthreads();

    // ---- phase 1a: count per-seg degree over the 16 sub-regions
    for (int s = 0; s < SUBS; s++) {
        int rbase = b * BUCKCAP + s * SUBCAP;
        int rcnt = gcur[b * SUBS + s] - rbase;
        for (int i = t; i < rcnt; i += 512)
            atomicAdd(&cnt64[pairs[rbase + i] >> 16], 1);
    }
    __syncthreads();
    if (t < 64) {  // wave 0: exclusive scan
        int v = cnt64[t];
        int s = v;
#pragma unroll
        for (int o = 1; o < 64; o <<= 1) {
            int u = __shfl_up(s, o);
            if (t >= o) s += u;
        }
        soff[t + 1] = s;
        if (t == 0) soff[0] = 0;
        scur[t] = s - v;
    }
    __syncthreads();
    // ---- phase 1b: place srcs per-dst-contiguous
    for (int s = 0; s < SUBS; s++) {
        int rbase = b * BUCKCAP + s * SUBCAP;
        int rcnt = gcur[b * SUBS + s] - rbase;
        for (int i = t; i < rcnt; i += 512) {
            unsigned p = pairs[rbase + i];
            int pos = atomicAdd(&scur[p >> 16], 1);
            ssrc[pos] = (unsigned short)(p & 0xFFFF);
        }
    }
    __syncthreads();

    // ---- phase 2: gather-reduce into sAgg (8 waves x 8 segs, paired 8B/lane)
    int h = lane >> 5, cl = lane & 31;
    int srcbase = isCon ? 0 : NPAT;   // concept dsts gather patient rows; vice versa
    const unsigned* xw = (const unsigned*)xin;
    for (int i = 0; i < 8; i++) {
        int d = wv * 8 + i;
        int beg = soff[d], end = soff[d + 1];
        float4 a0 = {0.f, 0.f, 0.f, 0.f}, a1 = {0.f, 0.f, 0.f, 0.f};
        int j = beg;
        if ((end - beg) & 1) {
            int s0 = ssrc[j];
            uint2 v = *(const uint2*)&xw[(size_t)(srcbase + s0) * 64 + 2 * cl];
            if (h == 0) {
                a0.x += bf2f_lo(v.x); a0.y += bf2f_hi(v.x);
                a0.z += bf2f_lo(v.y); a0.w += bf2f_hi(v.y);
            }
            j++;
        }
        for (; j + 3 < end; j += 4) {
            int sA = ssrc[j + h];
            int sB = ssrc[j + 2 + h];
            uint2 vA = *(const uint2*)&xw[(size_t)(srcbase + sA) * 64 + 2 * cl];
            uint2 vB = *(const uint2*)&xw[(size_t)(srcbase + sB) * 64 + 2 * cl];
            a0.x += bf2f_lo(vA.x); a0.y += bf2f_hi(vA.x);
            a0.z += bf2f_lo(vA.y); a0.w += bf2f_hi(vA.y);
            a1.x += bf2f_lo(vB.x); a1.y += bf2f_hi(vB.x);
            a1.z += bf2f_lo(vB.y); a1.w += bf2f_hi(vB.y);
        }
        if (j + 1 < end) {
            int sA = ssrc[j + h];
            uint2 vA = *(const uint2*)&xw[(size_t)(srcbase + sA) * 64 + 2 * cl];
            a0.x += bf2f_lo(vA.x); a0.y += bf2f_hi(vA.x);
            a0.z += bf2f_lo(vA.y); a0.w += bf2f_hi(vA.y);
        }
        a0.x += a1.x; a0.y += a1.y; a0.z += a1.z; a0.w += a1.w;
        a0.x += __shfl_xor(a0.x, 32);
        a0.y += __shfl_xor(a0.y, 32);
        a0.z += __shfl_xor(a0.z, 32);
        a0.w += __shfl_xor(a0.w, 32);
        if (h == 0) {
            float inv = 1.0f / (float)max(end - beg, 1);
            ushort4 o;
            o.x = f2bf(a0.x * inv); o.y = f2bf(a0.y * inv);
            o.z = f2bf(a0.z * inv); o.w = f2bf(a0.w * inv);
            *(ushort4*)&sAgg[d][4 * cl] = o;   // zero-deg rows -> 0 (required)
        }
    }

    // ---- phase 3: GEMM. K chunks 0..3 = sX @ Wroot, 4..7 = sAgg @ Wrel
    const float* W2 = isCon ? WrelC : WrelP;
    int m16 = lane & 15, kg = lane >> 4;
    f32x4 acc[4];
#pragma unroll
    for (int mt = 0; mt < 4; mt++) acc[mt] = (f32x4){0.f, 0.f, 0.f, 0.f};
    int bn = t & 127, kq = t >> 7;   // staging: col, k-phase (0..3)

#pragma unroll
    for (int kt = 0; kt < 8; kt++) {
        int k0 = (kt & 3) * 32;
        const float* bsrc = ((kt < 4) ? Wroot : W2) + (size_t)k0 * H;
        float bvals[8];
#pragma unroll
        for (int kk = 0; kk < 8; kk++) bvals[kk] = bsrc[(size_t)(kk * 4 + kq) * H + bn];
        __syncthreads();   // prev chunk's sBT reads done (also covers sAgg writes at kt=0)
#pragma unroll
        for (int kk = 0; kk < 8; kk++) sBT[bn][kk * 4 + kq] = f2bf(bvals[kk]);
        __syncthreads();
        const unsigned short (*Asrc)[STR] = (kt < 4) ? sX : sAgg;
        bf16x8 bfg = *(bf16x8*)&sBT[wv * 16 + m16][kg * 8];
        bf16x8 af[4];
#pragma unroll
        for (int mt = 0; mt < 4; mt++)
            af[mt] = *(bf16x8*)&Asrc[mt * 16 + m16][k0 + kg * 8];
#pragma unroll
        for (int mt = 0; mt < 4; mt++)
            acc[mt] = __builtin_amdgcn_mfma_f32_16x16x32_bf16(af[mt], bfg, acc[mt], 0, 0, 0);
    }

    // ---- epilogue: bias + relu, write valid rows
    float bv = bias[wv * 16 + m16];
    int lim = isCon ? NCON : NPAT;
    int lbase = isCon ? b * 64 : (b - RELSPLIT_B) * 64;
#pragma unroll
    for (int mt = 0; mt < 4; mt++) {
#pragma unroll
        for (int r = 0; r < 4; r++) {
            int lr = mt * 16 + kg * 4 + r;
            if (lbase + lr < lim) {
                int grow = row0 + lr;
                int gcol = wv * 16 + m16;
                float v = fmaxf(acc[mt][r] + bv, 0.f);
                if (Cout) Cout[(size_t)grow * H + gcol] = v;
                if (Cbf)  Cbf[(size_t)grow * H + gcol] = f2bf(v);
            }
        }
    }
}

// ============ proj GEMM (fp32 VALU): Cbf = A1 @ B1 + bias ============
#define BM 128
#define BK 8

struct GemmJob {
    const float* A1;
    const float* B1;
    const float* bias; unsigned short* Cbf;
    int lda1, K1, M;
};

__global__ void gemm_dual_kernel(GemmJob j0, GemmJob j1, int nb0) {
    __shared__ float sA[BK][BM];
    __shared__ float sB[BK][H];
    bool first = (int)blockIdx.x < nb0;
    GemmJob j = first ? j0 : j1;
    int bm = (first ? blockIdx.x : blockIdx.x - nb0) * BM;
    int tid = threadIdx.x;
    int am = tid >> 1;
    int ak = (tid & 1) * 4;
    int bk = tid >> 5;
    int bn = (tid & 31) * 4;
    int ty = tid >> 4;
    int tx = tid & 15;
    float acc[8][8] = {};
    for (int k0 = 0; k0 < j.K1; k0 += BK) {
        int gm = bm + am; if (gm >= j.M) gm = j.M - 1;
        float4 av = *(const float4*)&j.A1[(size_t)gm * j.lda1 + k0 + ak];
        float4 bv = *(const float4*)&j.B1[(size_t)(k0 + bk) * H + bn];
        __syncthreads();
        sA[ak + 0][am] = av.x; sA[ak + 1][am] = av.y;
        sA[ak + 2][am] = av.z; sA[ak + 3][am] = av.w;
        *(float4*)&sB[bk][bn] = bv;
        __syncthreads();
#pragma unroll
        for (int k = 0; k < BK; k++) {
            float a[8], bb[8];
            *(float4*)&a[0] = *(const float4*)&sA[k][ty * 8];
            *(float4*)&a[4] = *(const float4*)&sA[k][ty * 8 + 4];
            *(float4*)&bb[0] = *(const float4*)&sB[k][tx * 4];
            *(float4*)&bb[4] = *(const float4*)&sB[k][64 + tx * 4];
#pragma unroll
            for (int i = 0; i < 8; i++)
#pragma unroll
                for (int jj = 0; jj < 8; jj++)
                    acc[i][jj] += a[i] * bb[jj];
        }
    }
    float bcol[8];
    *(float4*)&bcol[0] = *(const float4*)&j.bias[tx * 4];
    *(float4*)&bcol[4] = *(const float4*)&j.bias[64 + tx * 4];
#pragma unroll
    for (int i = 0; i < 8; i++) {
        int gr = bm + ty * 8 + i;
        if (gr < j.M) {
#pragma unroll
            for (int q = 0; q < 8; q++) {
                float v = acc[i][q] + bcol[q];
                int gc = (q < 4) ? (tx * 4 + q) : (64 + tx * 4 + q - 4);
                j.Cbf[(size_t)gr * H + gc] = f2bf(v);
            }
        }
    }
}

// ============ launch ============

extern "C" void kernel_launch(void* const* d_in, const int* in_sizes, int n_in,
                              void* d_out, int out_size, void* d_ws, size_t ws_size,
                              hipStream_t stream) {
    const float* x_patient = (const float*)d_in[0];
    const float* x_concept = (const float*)d_in[1];
    const float* W_p       = (const float*)d_in[2];
    const float* b_p       = (const float*)d_in[3];
    const float* W_c       = (const float*)d_in[4];
    const float* b_c       = (const float*)d_in[5];
    const float* W_root    = (const float*)d_in[6];
    const float* b_root    = (const float*)d_in[7];
    const float* W_rel     = (const float*)d_in[8];
    const int*   src_pc    = (const int*)d_in[9];
    const int*   dst_pc    = (const int*)d_in[10];
    const int*   src_cp    = (const int*)d_in[11];
    const int*   dst_cp    = (const int*)d_in[12];
    float* out = (float*)d_out;

    char* w = (char*)d_ws;
    unsigned short* xbf0 = (unsigned short*)w; w += (size_t)NN * H * 2;     // 17.9 MB
    unsigned short* xbf1 = (unsigned short*)w; w += (size_t)NN * H * 2;     // 17.9 MB
    int* gcur = (int*)w;            w += (size_t)NBUCK * SUBS * 4;          // 70 KB
    unsigned* pairs = (unsigned*)w; w += (size_t)NBUCK * BUCKCAP * 4;       // 22.4 MB

    init_gcur_kernel<<<(NBUCK * SUBS + 255) / 256, 256, 0, stream>>>(gcur);
    binpack_kernel<<<NBB, 512, 0, stream>>>(dst_pc, src_pc, dst_cp, src_cp, gcur, pairs);

    const int PB = (NPAT + BM - 1) / BM;  // 391
    const int CB = (NCON + BM - 1) / BM;  // 157

    // projections -> xbf0
    {
        GemmJob jp = { x_patient, W_p, b_p, xbf0, 64, 64, NPAT };
        GemmJob jc = { x_concept, W_c, b_c, xbf0 + (size_t)NPAT * H, 128, 128, NCON };
        gemm_dual_kernel<<<PB + CB, 256, 0, stream>>>(jp, jc, PB);
    }

    for (int l = 0; l < 2; l++) {
        const unsigned short* xin = (l == 0) ? xbf0 : xbf1;
        const float* Wroot_l = W_root + (size_t)l * H * H;
        const float* Wrel_l0 = W_rel + (size_t)(l * 2 + 0) * H * H;
        const float* Wrel_l1 = W_rel + (size_t)(l * 2 + 1) * H * H;
        const float* br = b_root + (size_t)l * H;
        float* cOut = (l == 1) ? out : nullptr;
        unsigned short* cBf = (l == 0) ? xbf1 : nullptr;
        layer_fused_kernel<<<NBUCK, 512, 0, stream>>>(
            xin, pairs, gcur, Wroot_l, Wrel_l0, Wrel_l1, br, cOut, cBf);
    }
}

// Round 10
// 350.422 us; speedup vs baseline: 1.0755x; 1.0755x over previous
//
#include <hip/hip_runtime.h>
#include <hip/hip_bf16.h>

#define NPAT 50000
#define NCON 20000
#define NN   70000
#define EE   800000
#define H    128

#define NCON_AL  20032                 // concepts padded to 64-alignment
#define SEGN     (NCON_AL + NPAT)      // 70032 segment ids
#define NBUCK    1095                  // ceil(SEGN/64)
#define RELSPLIT_B 313                 // buckets [0,313) = concept dsts (rel0)
#define BUCKCAP  5120                  // pairs capacity per bucket (max fill ~2900)
#define SUBS     16                    // sub-regions per bucket
#define SUBCAP   (BUCKCAP / SUBS)      // 320 (max fill ~236)
#define BPE      4096                  // edges per binpack block
#define NBB      ((2 * EE + BPE - 1) / BPE)   // 391
#define CAP      4096                  // aggregate LDS edge capacity

// GEMM strips: each wave owns 32 rows x 128 cols
#define PSTRIPS  1563                  // ceil(NPAT/32)
#define CSTRIPS  625                   // NCON/32
#define TSTRIPS  (PSTRIPS + CSTRIPS)   // 2188
#define GBLK     ((TSTRIPS + 3) / 4)   // 547 blocks of 4 waves

// wbfT offsets (in shorts): weights pre-transposed to bf16 [n][k]
#define WPT_OFF    0                   // W_p^T   [128][64]
#define WCT_OFF    8192                // W_c^T   [128][128]
#define WROOTT_OFF 24576               // + l*16384
#define WRELT_OFF  57344               // + (l*2+r)*16384
#define WBFT_SHORTS 122880

typedef __attribute__((ext_vector_type(8))) short bf16x8;
typedef __attribute__((ext_vector_type(4))) float f32x4;

__device__ inline unsigned short f2bf(float f) {
    unsigned u = __float_as_uint(f);
    unsigned r = (u + 0x7FFFu + ((u >> 16) & 1u)) >> 16;
    return (unsigned short)r;
}
__device__ inline float bf2f_lo(unsigned v) { return __uint_as_float(v << 16); }
__device__ inline float bf2f_hi(unsigned v) { return __uint_as_float(v & 0xFFFF0000u); }

// ============ prep: init gcur cursors (blocks 0..68) + weight transpose->bf16 (69..128) ====
__global__ __launch_bounds__(256) void prep_kernel(
        const float* __restrict__ Wp, const float* __restrict__ Wc,
        const float* __restrict__ Wroot, const float* __restrict__ Wrel,
        unsigned short* __restrict__ wbfT, int* __restrict__ gcur) {
    int b = blockIdx.x, t = threadIdx.x;
    if (b < 69) {
        int j = b * 256 + t;
        if (j < NBUCK * SUBS) gcur[j] = (j >> 4) * BUCKCAP + (j & (SUBS - 1)) * SUBCAP;
        return;
    }
    int wb = b - 69;                       // 0..59; 2048 elems per block
    const float* src; int K, outoff, eoff;
    if (wb < 4) { src = Wp; K = 64; outoff = WPT_OFF; eoff = wb * 2048; }
    else {
        int m = (wb - 4) >> 3, sub = (wb - 4) & 7;
        eoff = sub * 2048;
        if (m == 0)      { src = Wc;                    K = 128; outoff = WCT_OFF; }
        else if (m < 3)  { src = Wroot + (m - 1) * 16384; K = 128; outoff = WROOTT_OFF + (m - 1) * 16384; }
        else             { src = Wrel + (m - 3) * 16384;  K = 128; outoff = WRELT_OFF + (m - 3) * 16384; }
    }
    int e = eoff + t * 8;                  // src [K][128] row-major; 8 consecutive = same k
    int k = e >> 7, n0 = e & 127;
    float4 v0 = *(const float4*)&src[e];
    float4 v1 = *(const float4*)&src[e + 4];
    unsigned short o[8] = { f2bf(v0.x), f2bf(v0.y), f2bf(v0.z), f2bf(v0.w),
                            f2bf(v1.x), f2bf(v1.y), f2bf(v1.z), f2bf(v1.w) };
#pragma unroll
    for (int j = 0; j < 8; j++) wbfT[outoff + (n0 + j) * K + k] = o[j];
}

// ============ binpack: 512 thr, LDS counting sort by bucket, run-reserve, write (R8) ====
__global__ __launch_bounds__(512) void binpack_kernel(
        const int* __restrict__ dst_pc, const int* __restrict__ src_pc,
        const int* __restrict__ dst_cp, const int* __restrict__ src_cp,
        int* __restrict__ gcur, unsigned* __restrict__ pairs) {
    __shared__ unsigned sval[BPE];
    __shared__ unsigned short sbkt[BPE];
    __shared__ int cnt[NBUCK];
    __shared__ int delta[NBUCK];
    __shared__ int partial[512];
    int t = threadIdx.x, blk = blockIdx.x;
    int base = blk * BPE;
    int n = min(BPE, 2 * EE - base);

    for (int i = t; i < NBUCK; i += 512) cnt[i] = 0;
    __syncthreads();

    unsigned pay[8];
    int bkt[8];
#pragma unroll
    for (int q = 0; q < 8; q++) {
        int li = q * 512 + t;
        bkt[q] = -1;
        if (li < n) {
            int i = base + li;
            int seg, src;
            if (i < EE) { seg = dst_pc[i];                src = src_pc[i]; }
            else        { seg = NCON_AL + dst_cp[i - EE]; src = src_cp[i - EE]; }
            int b = seg >> 6;
            pay[q] = (unsigned)src | ((unsigned)(seg & 63) << 16);
            bkt[q] = b;
            atomicAdd(&cnt[b], 1);
        }
    }
    __syncthreads();

    const int PER = (NBUCK + 511) / 512;   // 3
    int beg = t * PER;
    int s = 0;
#pragma unroll
    for (int k = 0; k < PER; k++) { int i = beg + k; if (i < NBUCK) s += cnt[i]; }
    partial[t] = s;
    __syncthreads();
    for (int o = 1; o < 512; o <<= 1) {
        int v = (t >= o) ? partial[t - o] : 0;
        __syncthreads();
        partial[t] += v;
        __syncthreads();
    }
    int run = partial[t] - s;
    int sub = blk & (SUBS - 1);
    int prefk[PER];
#pragma unroll
    for (int k = 0; k < PER; k++) {
        int i = beg + k;
        if (i < NBUCK) {
            prefk[k] = run;
            int c = cnt[i];
            if (c > 0) {
                int gb = atomicAdd(&gcur[i * SUBS + sub], c);
                delta[i] = gb - run;
            }
            run += c;
        }
    }
    __syncthreads();
#pragma unroll
    for (int k = 0; k < PER; k++) { int i = beg + k; if (i < NBUCK) cnt[i] = prefk[k]; }
    __syncthreads();

#pragma unroll
    for (int q = 0; q < 8; q++) {
        if (bkt[q] >= 0) {
            int b = bkt[q];
            int pos = atomicAdd(&cnt[b], 1);
            sval[pos] = pay[q];
            sbkt[pos] = (unsigned short)b;
        }
    }
    __syncthreads();
    for (int i = t; i < n; i += 512)
        pairs[delta[sbkt[i]] + i] = sval[i];
}

// ============ mean aggregation: block per bucket, 512 thr; paired 8B/lane gather (R8) ====
__global__ __launch_bounds__(512) void aggregate_kernel(
        const unsigned short* __restrict__ xbf, const unsigned* __restrict__ pairs,
        const int* __restrict__ gcur, unsigned short* __restrict__ aggn) {
    __shared__ int cnt64[64];
    __shared__ int soff[65];
    __shared__ int scur[64];
    __shared__ unsigned short ssrc[CAP];
    int t = threadIdx.x, b = blockIdx.x;
    if (t < 64) cnt64[t] = 0;
    __syncthreads();
    for (int s = 0; s < SUBS; s++) {
        int rbase = b * BUCKCAP + s * SUBCAP;
        int rcnt = gcur[b * SUBS + s] - rbase;
        for (int i = t; i < rcnt; i += 512)
            atomicAdd(&cnt64[pairs[rbase + i] >> 16], 1);
    }
    __syncthreads();
    if (t < 64) {
        int v = cnt64[t];
        int s = v;
#pragma unroll
        for (int o = 1; o < 64; o <<= 1) {
            int u = __shfl_up(s, o);
            if (t >= o) s += u;
        }
        soff[t + 1] = s;
        if (t == 0) soff[0] = 0;
        scur[t] = s - v;
    }
    __syncthreads();
    for (int s = 0; s < SUBS; s++) {
        int rbase = b * BUCKCAP + s * SUBCAP;
        int rcnt = gcur[b * SUBS + s] - rbase;
        for (int i = t; i < rcnt; i += 512) {
            unsigned p = pairs[rbase + i];
            int pos = atomicAdd(&scur[p >> 16], 1);
            ssrc[pos] = (unsigned short)(p & 0xFFFF);
        }
    }
    __syncthreads();
    int wv = t >> 6, lane = t & 63;
    int h = lane >> 5, cl = lane & 31;
    int rowbase = (b < RELSPLIT_B) ? 0 : NPAT;
    int seglim  = (b < RELSPLIT_B) ? NCON : SEGN;
    const unsigned* xw = (const unsigned*)xbf;
    for (int i = 0; i < 8; i++) {
        int d = wv * 8 + i;
        int seg = b * 64 + d;
        if (seg >= seglim) continue;
        int beg = soff[d], end = soff[d + 1];
        float4 a0 = {0.f, 0.f, 0.f, 0.f}, a1 = {0.f, 0.f, 0.f, 0.f};
        int j = beg;
        if ((end - beg) & 1) {
            int s0 = ssrc[j];
            uint2 v = *(const uint2*)&xw[(size_t)(rowbase + s0) * 64 + 2 * cl];
            if (h == 0) {
                a0.x += bf2f_lo(v.x); a0.y += bf2f_hi(v.x);
                a0.z += bf2f_lo(v.y); a0.w += bf2f_hi(v.y);
            }
            j++;
        }
        for (; j + 3 < end; j += 4) {
            int sA = ssrc[j + h];
            int sB = ssrc[j + 2 + h];
            uint2 vA = *(const uint2*)&xw[(size_t)(rowbase + sA) * 64 + 2 * cl];
            uint2 vB = *(const uint2*)&xw[(size_t)(rowbase + sB) * 64 + 2 * cl];
            a0.x += bf2f_lo(vA.x); a0.y += bf2f_hi(vA.x);
            a0.z += bf2f_lo(vA.y); a0.w += bf2f_hi(vA.y);
            a1.x += bf2f_lo(vB.x); a1.y += bf2f_hi(vB.x);
            a1.z += bf2f_lo(vB.y); a1.w += bf2f_hi(vB.y);
        }
        if (j + 1 < end) {
            int sA = ssrc[j + h];
            uint2 vA = *(const uint2*)&xw[(size_t)(rowbase + sA) * 64 + 2 * cl];
            a0.x += bf2f_lo(vA.x); a0.y += bf2f_hi(vA.x);
            a0.z += bf2f_lo(vA.y); a0.w += bf2f_hi(vA.y);
        }
        a0.x += a1.x; a0.y += a1.y; a0.z += a1.z; a0.w += a1.w;
        a0.x += __shfl_xor(a0.x, 32);
        a0.y += __shfl_xor(a0.y, 32);
        a0.z += __shfl_xor(a0.z, 32);
        a0.w += __shfl_xor(a0.w, 32);
        if (h == 0) {
            float inv = 1.0f / (float)max(end - beg, 1);
            ushort4 o;
            o.x = f2bf(a0.x * inv); o.y = f2bf(a0.y * inv);
            o.z = f2bf(a0.z * inv); o.w = f2bf(a0.w * inv);
            *(ushort4*)&aggn[(size_t)seg * H + 4 * cl] = o;  // zero-deg segs write 0 (required)
        }
    }
}

// ============ proj: barrier-free MFMA. Wave owns 32 rows; A fp32 -> bf16 in-reg ============
__global__ __launch_bounds__(256) void proj_kernel(
        const float* __restrict__ xp, const float* __restrict__ xc,
        const unsigned short* __restrict__ wbfT,
        const float* __restrict__ bp, const float* __restrict__ bc,
        unsigned short* __restrict__ Cbf) {
    int strip = blockIdx.x * 4 + ((int)threadIdx.x >> 6);
    if (strip >= TSTRIPS) return;
    int lane = threadIdx.x & 63;
    int m16 = lane & 15, kg = lane >> 4;
    bool isP = strip < PSTRIPS;
    const float* A = isP ? xp : xc;
    int K = isP ? 64 : 128;
    int M = isP ? NPAT : NCON;
    int nkt = K >> 5;
    const unsigned short* BT = wbfT + (isP ? WPT_OFF : WCT_OFF);
    const float* bias = isP ? bp : bc;
    int r0 = (isP ? strip : strip - PSTRIPS) * 32;
    int outbase = isP ? 0 : NPAT;
    int arow0 = min(r0 + m16, M - 1);
    int arow1 = min(r0 + 16 + m16, M - 1);

    f32x4 acc[2][8];
#pragma unroll
    for (int mt = 0; mt < 2; mt++)
#pragma unroll
        for (int nt = 0; nt < 8; nt++) acc[mt][nt] = (f32x4){0.f, 0.f, 0.f, 0.f};

    for (int kt = 0; kt < nkt; kt++) {
        int kk = kt * 32 + kg * 8;
        bf16x8 af[2];
#pragma unroll
        for (int mt = 0; mt < 2; mt++) {
            const float* Ar = A + (size_t)(mt ? arow1 : arow0) * K + kk;
            float4 v0 = *(const float4*)Ar;
            float4 v1 = *(const float4*)(Ar + 4);
            bf16x8 a;
            a[0] = (short)f2bf(v0.x); a[1] = (short)f2bf(v0.y);
            a[2] = (short)f2bf(v0.z); a[3] = (short)f2bf(v0.w);
            a[4] = (short)f2bf(v1.x); a[5] = (short)f2bf(v1.y);
            a[6] = (short)f2bf(v1.z); a[7] = (short)f2bf(v1.w);
            af[mt] = a;
        }
        bf16x8 bfg[8];
#pragma unroll
        for (int nt = 0; nt < 8; nt++)
            bfg[nt] = *(const bf16x8*)&BT[(size_t)(nt * 16 + m16) * K + kk];
#pragma unroll
        for (int mt = 0; mt < 2; mt++)
#pragma unroll
            for (int nt = 0; nt < 8; nt++)
                acc[mt][nt] = __builtin_amdgcn_mfma_f32_16x16x32_bf16(
                    af[mt], bfg[nt], acc[mt][nt], 0, 0, 0);
    }
    float bv[8];
#pragma unroll
    for (int nt = 0; nt < 8; nt++) bv[nt] = bias[nt * 16 + m16];
#pragma unroll
    for (int mt = 0; mt < 2; mt++)
#pragma unroll
        for (int r = 0; r < 4; r++) {
            int lr = r0 + mt * 16 + kg * 4 + r;
            if (lr < M) {
                size_t orow = (size_t)(outbase + lr);
#pragma unroll
                for (int nt = 0; nt < 8; nt++)
                    Cbf[orow * H + nt * 16 + m16] = f2bf(acc[mt][nt][r] + bv[nt]);
            }
        }
}

// ============ layer GEMM: barrier-free MFMA. C = x@Wroot + agg@Wrel + bias, relu ============
__global__ __launch_bounds__(256) void layer_kernel(
        const unsigned short* __restrict__ xin, const unsigned short* __restrict__ aggn,
        const unsigned short* __restrict__ wbfT, int l, const float* __restrict__ bias,
        float* __restrict__ Cout, unsigned short* __restrict__ Cbf) {
    int strip = blockIdx.x * 4 + ((int)threadIdx.x >> 6);
    if (strip >= TSTRIPS) return;
    int lane = threadIdx.x & 63;
    int m16 = lane & 15, kg = lane >> 4;
    bool isP = strip < PSTRIPS;
    int M = isP ? NPAT : NCON;
    int r0 = (isP ? strip : strip - PSTRIPS) * 32;
    const unsigned short* A1 = xin + (size_t)(isP ? 0 : NPAT) * H;
    const unsigned short* A2 = aggn + (size_t)(isP ? NCON_AL : 0) * H;
    const unsigned short* BrootT = wbfT + WROOTT_OFF + l * 16384;
    const unsigned short* BrelT  = wbfT + WRELT_OFF + (l * 2 + (isP ? 1 : 0)) * 16384;
    int arow0 = min(r0 + m16, M - 1);
    int arow1 = min(r0 + 16 + m16, M - 1);

    f32x4 acc[2][8];
#pragma unroll
    for (int mt = 0; mt < 2; mt++)
#pragma unroll
        for (int nt = 0; nt < 8; nt++) acc[mt][nt] = (f32x4){0.f, 0.f, 0.f, 0.f};

#pragma unroll
    for (int kt = 0; kt < 8; kt++) {
        int kk = (kt & 3) * 32 + kg * 8;
        const unsigned short* Ab = (kt < 4) ? A1 : A2;
        const unsigned short* Bb = (kt < 4) ? BrootT : BrelT;
        bf16x8 af0 = *(const bf16x8*)&Ab[(size_t)arow0 * H + kk];
        bf16x8 af1 = *(const bf16x8*)&Ab[(size_t)arow1 * H + kk];
        bf16x8 bfg[8];
#pragma unroll
        for (int nt = 0; nt < 8; nt++)
            bfg[nt] = *(const bf16x8*)&Bb[(size_t)(nt * 16 + m16) * 128 + kk];
#pragma unroll
        for (int nt = 0; nt < 8; nt++) {
            acc[0][nt] = __builtin_amdgcn_mfma_f32_16x16x32_bf16(af0, bfg[nt], acc[0][nt], 0, 0, 0);
            acc[1][nt] = __builtin_amdgcn_mfma_f32_16x16x32_bf16(af1, bfg[nt], acc[1][nt], 0, 0, 0);
        }
    }
    float bv[8];
#pragma unroll
    for (int nt = 0; nt < 8; nt++) bv[nt] = bias[nt * 16 + m16];
    int outbase = isP ? 0 : NPAT;
#pragma unroll
    for (int mt = 0; mt < 2; mt++)
#pragma unroll
        for (int r = 0; r < 4; r++) {
            int lr = r0 + mt * 16 + kg * 4 + r;
            if (lr < M) {
                size_t orow = (size_t)(outbase + lr);
#pragma unroll
                for (int nt = 0; nt < 8; nt++) {
                    float v = fmaxf(acc[mt][nt][r] + bv[nt], 0.f);
                    if (Cout) Cout[orow * H + nt * 16 + m16] = v;
                    if (Cbf)  Cbf[orow * H + nt * 16 + m16] = f2bf(v);
                }
            }
        }
}

// ============ launch ============

extern "C" void kernel_launch(void* const* d_in, const int* in_sizes, int n_in,
                              void* d_out, int out_size, void* d_ws, size_t ws_size,
                              hipStream_t stream) {
    const float* x_patient = (const float*)d_in[0];
    const float* x_concept = (const float*)d_in[1];
    const float* W_p       = (const float*)d_in[2];
    const float* b_p       = (const float*)d_in[3];
    const float* W_c       = (const float*)d_in[4];
    const float* b_c       = (const float*)d_in[5];
    const float* W_root    = (const float*)d_in[6];
    const float* b_root    = (const float*)d_in[7];
    const float* W_rel     = (const float*)d_in[8];
    const int*   src_pc    = (const int*)d_in[9];
    const int*   dst_pc    = (const int*)d_in[10];
    const int*   src_cp    = (const int*)d_in[11];
    const int*   dst_cp    = (const int*)d_in[12];
    float* out = (float*)d_out;

    char* w = (char*)d_ws;
    unsigned short* xbf0 = (unsigned short*)w; w += (size_t)NN * H * 2;     // 17.9 MB
    unsigned short* xbf1 = (unsigned short*)w; w += (size_t)NN * H * 2;     // 17.9 MB
    unsigned short* aggn = (unsigned short*)w; w += (size_t)SEGN * H * 2;   // 17.9 MB
    unsigned short* wbfT = (unsigned short*)w; w += (size_t)WBFT_SHORTS * 2; // 240 KB
    int* gcur = (int*)w;            w += (size_t)NBUCK * SUBS * 4;          // 70 KB
    unsigned* pairs = (unsigned*)w; w += (size_t)NBUCK * BUCKCAP * 4;       // 22.4 MB

    // 1. prep: gcur init + weight transpose/convert
    prep_kernel<<<129, 256, 0, stream>>>(W_p, W_c, W_root, W_rel, wbfT, gcur);
    // 2. projections -> xbf0 (MFMA, barrier-free)
    proj_kernel<<<GBLK, 256, 0, stream>>>(x_patient, x_concept, wbfT, b_p, b_c, xbf0);
    // 3. edge binning
    binpack_kernel<<<NBB, 512, 0, stream>>>(dst_pc, src_pc, dst_cp, src_cp, gcur, pairs);
    // 4-7. layers
    for (int l = 0; l < 2; l++) {
        const unsigned short* xin = (l == 0) ? xbf0 : xbf1;
        aggregate_kernel<<<NBUCK, 512, 0, stream>>>(xin, pairs, gcur, aggn);
        float* cOut = (l == 1) ? out : nullptr;
        unsigned short* cBf = (l == 0) ? xbf1 : nullptr;
        layer_kernel<<<GBLK, 256, 0, stream>>>(xin, aggn, wbfT, l,
                                               b_root + (size_t)l * H, cOut, cBf);
    }
}